// Round 2
// baseline (212.831 us; speedup 1.0000x reference)
//
#include <hip/hip_runtime.h>
#include <math.h>

// ---- static config (mirrors reference) ----
#define BB 16
#define AA 3
#define NCC 80
#define WW 76
#define MM 32
#define CELLS_PER_IMG (AA * WW * WW)          // 17328
#define NDECODE (BB * CELLS_PER_IMG * 85)     // 23,566,080
#define NCELLS (BB * CELLS_PER_IMG)           // 277,248
#define N4 (NDECODE / 4)                      // 5,891,520 float4s (N4 % 64 == 0)

typedef float vfloat4 __attribute__((ext_vector_type(4)));

__constant__ float c_anchor[9][2] = {
    {10.f,13.f},{16.f,30.f},{33.f,23.f},{30.f,61.f},{62.f,45.f},
    {59.f,119.f},{116.f,90.f},{156.f,198.f},{373.f,326.f}};

#define LOG2E 1.4426950408889634f

__device__ __forceinline__ float fast_sigmoid(float x) {
    return __builtin_amdgcn_rcpf(1.0f + __builtin_amdgcn_exp2f(-x * LOG2E));
}

__device__ __forceinline__ vfloat4 sig4(vfloat4 v) {
    vfloat4 o;
    o.x = fast_sigmoid(v.x);
    o.y = fast_sigmoid(v.y);
    o.z = fast_sigmoid(v.z);
    o.w = fast_sigmoid(v.w);
    return o;
}

// ---------------------------------------------------------------------------
// Kernel 1: decode — PURE STREAM. load dwordx4, 4x sigmoid, store dwordx4.
// No divergence, no scattered stores, no integer chains beyond addressing.
// Box channels get (wrong) plain sigmoid here; kernel 2 overwrites them with
// correct values before the harness reads dec (stream-ordered).
// Diagnostic intent: rounds 0-1 both ran ~60us at ~3.2 TB/s traffic while the
// harness fill hits 6.6 TB/s; if THIS still runs ~58us, the stream rate is a
// platform ceiling, not a kernel defect.
// Normal (non-NT) stores: dec lines stay L3-resident for kernel 2's 16B fixes.
// ---------------------------------------------------------------------------
__global__ __launch_bounds__(256) void decode_kernel(const vfloat4* __restrict__ in,
                                                     vfloat4* __restrict__ out) {
    unsigned tid  = blockIdx.x * 256u + threadIdx.x;
    unsigned wave = tid >> 6;
    unsigned lane = tid & 63u;
    unsigned i0 = wave * 256u + lane;       // wave-tiled: 1KB contiguous per instr
    unsigned i1 = i0 + 64u;
    unsigned i2 = i0 + 128u;
    unsigned i3 = i0 + 192u;
    const unsigned last = N4 - 1u;

    // clamped unconditional loads -> 4 independent loads in flight
    vfloat4 v0 = in[i0 < last ? i0 : last];
    vfloat4 v1 = in[i1 < last ? i1 : last];
    vfloat4 v2 = in[i2 < last ? i2 : last];
    vfloat4 v3 = in[i3 < last ? i3 : last];

    bool p0 = i0 < N4, p1 = i1 < N4, p2 = i2 < N4, p3 = i3 < N4;  // wave-uniform

    if (p0) out[i0] = sig4(v0);
    if (p1) out[i1] = sig4(v1);
    if (p2) out[i2] = sig4(v2);
    if (p3) out[i3] = sig4(v3);
}

// ---------------------------------------------------------------------------
// Kernel 2: per-cell. Recomputes the 4 box values straight from `in`
// (16B gather @ base=85*cell, ~1.2 lines/cell, mostly L3-resident from
// kernel 1's read), writes them into dec (the box-channel fix), uses them for
// the 32-GT max-IoU -> noobj, zeroes obj. `boxes` scratch stream eliminated.
// Formulas bit-identical to the previously passing fix_chunk:
//   c0: sig + cell%76   c1: sig + (cell/76)%76
//   c2: exp2(x*log2e) * aw*0.125   c3: exp2(x*log2e) * ah*0.125
// ---------------------------------------------------------------------------
__global__ void noobj_kernel(const float* __restrict__ in, const float* __restrict__ gt,
                             float* __restrict__ dec,
                             float* __restrict__ noobj, float* __restrict__ obj) {
    __shared__ float4 sbox[MM];
    int b = blockIdx.y;
    int t = threadIdx.x;
    if (t < MM) {
        const float* g = gt + (size_t)(b * MM + t) * 6;
        float cx = g[1], cy = g[2], gw = g[3], gh = g[4];
        sbox[t] = make_float4((cx - gw * 0.5f) * 608.0f, (cy - gh * 0.5f) * 608.0f,
                              (cx + gw * 0.5f) * 608.0f, (cy + gh * 0.5f) * 608.0f);
    }
    __syncthreads();
    int n = blockIdx.x * blockDim.x + t;
    if (n >= CELLS_PER_IMG) return;
    size_t idx  = (size_t)b * CELLS_PER_IMG + n;
    size_t base = idx * 85u;

    // gather raw tx,ty,tw,th (4 dword loads; 4B-aligned)
    float tx = in[base + 0], ty = in[base + 1];
    float tw = in[base + 2], th = in[base + 3];

    unsigned cell = (unsigned)idx;
    unsigned tq  = cell / 76u;
    unsigned gi  = cell - tq * 76u;          // cell % 76
    unsigned tq2 = tq / 76u;
    unsigned gj  = tq - tq2 * 76u;           // (cell/76) % 76
    unsigned a   = tq2 % 3u;                 // anchor index
    float aw = (a == 0u) ? 1.25f  : ((a == 1u) ? 2.0f  : 4.125f); // {10,16,33}*0.125
    float ah = (a == 0u) ? 1.625f : ((a == 1u) ? 3.75f : 2.875f); // {13,30,23}*0.125

    float px = fast_sigmoid(tx) + (float)gi;
    float py = fast_sigmoid(ty) + (float)gj;
    float pw = __builtin_amdgcn_exp2f(tw * LOG2E) * aw;
    float ph = __builtin_amdgcn_exp2f(th * LOG2E) * ah;

    // fix the box channels in dec (lines hot in L2/L3 from kernel 1's stores)
    dec[base + 0] = px;
    dec[base + 1] = py;
    dec[base + 2] = pw;
    dec[base + 3] = ph;

    // replicate reference FP order: (val)/W * INPUTW
    float x1 = (px - pw * 0.5f) / 76.0f * 608.0f;
    float y1 = (py - ph * 0.5f) / 76.0f * 608.0f;
    float x2 = (px + pw * 0.5f) / 76.0f * 608.0f;
    float y2 = (py + ph * 0.5f) / 76.0f * 608.0f;
    float area2 = (x2 - x1) * (y2 - y1);
    float best = 0.0f;
#pragma unroll
    for (int m = 0; m < MM; ++m) {
        float4 gb = sbox[m];
        float area1 = (gb.z - gb.x) * (gb.w - gb.y);
        float ltx = fmaxf(gb.x, x1), lty = fmaxf(gb.y, y1);
        float rbx = fminf(gb.z, x2), rby = fminf(gb.w, y2);
        float inter = fmaxf(rbx - ltx, 0.0f) * fmaxf(rby - lty, 0.0f);
        float iou = inter * __builtin_amdgcn_rcpf(area1 + area2 - inter);
        best = fmaxf(best, iou);
    }
    noobj[idx] = (best <= 0.5f) ? 1.0f : 0.0f;
    obj[idx] = 0.0f;
}

// ---------------------------------------------------------------------------
// Kernel 3: per-GT best-anchor argmax. (unchanged; runs after kernel 2)
// ---------------------------------------------------------------------------
__global__ void assign_kernel(const float* __restrict__ gt,
                              float* __restrict__ noobj, float* __restrict__ obj) {
    int r = blockIdx.x * blockDim.x + threadIdx.x;
    if (r >= BB * MM) return;
    const float* g = gt + (size_t)r * 6;
    float cx = g[1], cy = g[2], gw = g[3], gh = g[4];
    float gx1 = (cx - gw * 0.5f) * 608.0f, gy1 = (cy - gh * 0.5f) * 608.0f;
    float gx2 = (cx + gw * 0.5f) * 608.0f, gy2 = (cy + gh * 0.5f) * 608.0f;
    float area_g = (gx2 - gx1) * (gy2 - gy1);
    int best = 0;
    float bestv = -1.0f;
#pragma unroll
    for (int k = 0; k < 9; ++k) {
        float ow = c_anchor[k][0] / 608.0f, oh = c_anchor[k][1] / 608.0f;
        float ax1 = (cx - ow * 0.5f) * 608.0f, ay1 = (cy - oh * 0.5f) * 608.0f;
        float ax2 = (cx + ow * 0.5f) * 608.0f, ay2 = (cy + oh * 0.5f) * 608.0f;
        float ltx = fmaxf(gx1, ax1), lty = fmaxf(gy1, ay1);
        float rbx = fminf(gx2, ax2), rby = fminf(gy2, ay2);
        float inter = fmaxf(rbx - ltx, 0.0f) * fmaxf(rby - lty, 0.0f);
        float area_a = (ax2 - ax1) * (ay2 - ay1);
        float v = inter / (area_g + area_a - inter);
        if (v > bestv) { bestv = v; best = k; }
    }
    if (best < AA) {
        int b = r / MM;
        int gi = (int)(cx * 76.0f);
        int gj = (int)(cy * 76.0f);
        int flat = ((b * AA + best) * WW + gi) * WW + gj;
        obj[flat] = 1.0f;
        noobj[flat] = 0.0f;
    }
}

extern "C" void kernel_launch(void* const* d_in, const int* in_sizes, int n_in,
                              void* d_out, int out_size, void* d_ws, size_t ws_size,
                              hipStream_t stream) {
    const float* pred = (const float*)d_in[0];
    const float* gt   = (const float*)d_in[1];
    float* dec   = (float*)d_out;            // 23,566,080
    float* noobj = dec + NDECODE;            //    277,248
    float* obj   = noobj + NCELLS;           //    277,248
    (void)d_ws; (void)ws_size;               // boxes scratch eliminated

    const int nblocks = (N4 + 1023) / 1024;  // 4 float4s/thread, wave-tiled
    decode_kernel<<<nblocks, 256, 0, stream>>>(
        (const vfloat4*)pred, (vfloat4*)dec);

    dim3 gb((CELLS_PER_IMG + 255) / 256, BB);
    noobj_kernel<<<gb, 256, 0, stream>>>(pred, gt, dec, noobj, obj);

    assign_kernel<<<2, 256, 0, stream>>>(gt, noobj, obj);
}

// Round 4
// 205.640 us; speedup vs baseline: 1.0350x; 1.0350x over previous
//
#include <hip/hip_runtime.h>
#include <math.h>

// ---- static config (mirrors reference) ----
#define BB 16
#define AA 3
#define NCC 80
#define WW 76
#define MM 32
#define CELLS_PER_IMG (AA * WW * WW)          // 17328
#define NDECODE (BB * CELLS_PER_IMG * 85)     // 23,566,080
#define NCELLS (BB * CELLS_PER_IMG)           // 277,248
#define N4 (NDECODE / 4)                      // 5,891,520 float4s (N4 % 64 == 0)

typedef float vfloat4 __attribute__((ext_vector_type(4)));

__constant__ float c_anchor[9][2] = {
    {10.f,13.f},{16.f,30.f},{33.f,23.f},{30.f,61.f},{62.f,45.f},
    {59.f,119.f},{116.f,90.f},{156.f,198.f},{373.f,326.f}};

#define LOG2E 1.4426950408889634f

__device__ __forceinline__ float fast_sigmoid(float x) {
    return __builtin_amdgcn_rcpf(1.0f + __builtin_amdgcn_exp2f(-x * LOG2E));
}

__device__ __forceinline__ vfloat4 sig4(vfloat4 v) {
    vfloat4 o;
    o.x = fast_sigmoid(v.x);
    o.y = fast_sigmoid(v.y);
    o.z = fast_sigmoid(v.z);
    o.w = fast_sigmoid(v.w);
    return o;
}

// ---------------------------------------------------------------------------
// Kernel 1: decode — PURE STREAM. load dwordx4, 4x sigmoid, NT store dwordx4.
// NT stores (vs round 2's normal stores): dec is write-once and never read by
// our kernels; keeping 94 MB of dirty dec lines out of L3 (a) leaves pred
// fully L3-resident for kernel 2's box-channel gather and (b) tests the
// round1->round2 correlation where normal stores coincided with the harness
// poison fills dropping 6.6 -> 5.5 TB/s (+26 us of measured window).
// Box channels get plain sigmoid here; kernel 2 overwrites them (stream
// order) before the harness reads dec.
// ---------------------------------------------------------------------------
__global__ __launch_bounds__(256) void decode_kernel(const vfloat4* __restrict__ in,
                                                     vfloat4* __restrict__ out) {
    unsigned tid  = blockIdx.x * 256u + threadIdx.x;
    unsigned wave = tid >> 6;
    unsigned lane = tid & 63u;
    unsigned i0 = wave * 256u + lane;       // wave-tiled: 1KB contiguous per instr
    unsigned i1 = i0 + 64u;
    unsigned i2 = i0 + 128u;
    unsigned i3 = i0 + 192u;
    const unsigned last = N4 - 1u;

    // clamped unconditional loads -> 4 independent loads in flight
    vfloat4 v0 = in[i0 < last ? i0 : last];
    vfloat4 v1 = in[i1 < last ? i1 : last];
    vfloat4 v2 = in[i2 < last ? i2 : last];
    vfloat4 v3 = in[i3 < last ? i3 : last];

    bool p0 = i0 < N4, p1 = i1 < N4, p2 = i2 < N4, p3 = i3 < N4;  // wave-uniform

    vfloat4 o0 = sig4(v0);
    vfloat4 o1 = sig4(v1);
    vfloat4 o2 = sig4(v2);
    vfloat4 o3 = sig4(v3);

    if (p0) __builtin_nontemporal_store(o0, &out[i0]);
    if (p1) __builtin_nontemporal_store(o1, &out[i1]);
    if (p2) __builtin_nontemporal_store(o2, &out[i2]);
    if (p3) __builtin_nontemporal_store(o3, &out[i3]);
}

// ---------------------------------------------------------------------------
// Kernel 2: per-cell. Recomputes the 4 box values straight from `in`
// (16B gather @ base=85*cell; pred stays L3-resident since dec bypassed L3),
// writes them into dec (16B partial-line fix; masked writes, no RMW fetch
// needed), uses them for the 32-GT max-IoU -> noobj, zeroes obj.
// Formulas bit-identical to the previously passing versions:
//   c0: sig + cell%76   c1: sig + (cell/76)%76
//   c2: exp2(x*log2e) * aw*0.125   c3: exp2(x*log2e) * ah*0.125
// ---------------------------------------------------------------------------
__global__ void noobj_kernel(const float* __restrict__ in, const float* __restrict__ gt,
                             float* __restrict__ dec,
                             float* __restrict__ noobj, float* __restrict__ obj) {
    __shared__ float4 sbox[MM];
    int b = blockIdx.y;
    int t = threadIdx.x;
    if (t < MM) {
        const float* g = gt + (size_t)(b * MM + t) * 6;
        float cx = g[1], cy = g[2], gw = g[3], gh = g[4];
        sbox[t] = make_float4((cx - gw * 0.5f) * 608.0f, (cy - gh * 0.5f) * 608.0f,
                              (cx + gw * 0.5f) * 608.0f, (cy + gh * 0.5f) * 608.0f);
    }
    __syncthreads();
    int n = blockIdx.x * blockDim.x + t;
    if (n >= CELLS_PER_IMG) return;
    size_t idx  = (size_t)b * CELLS_PER_IMG + n;
    size_t base = idx * 85u;

    // gather raw tx,ty,tw,th (independent dword loads; contiguous 16B window)
    float tx = in[base + 0], ty = in[base + 1];
    float tw = in[base + 2], th = in[base + 3];

    unsigned cell = (unsigned)idx;
    unsigned tq  = cell / 76u;
    unsigned gi  = cell - tq * 76u;          // cell % 76
    unsigned tq2 = tq / 76u;
    unsigned gj  = tq - tq2 * 76u;           // (cell/76) % 76
    unsigned a   = tq2 % 3u;                 // anchor index
    float aw = (a == 0u) ? 1.25f  : ((a == 1u) ? 2.0f  : 4.125f); // {10,16,33}*0.125
    float ah = (a == 0u) ? 1.625f : ((a == 1u) ? 3.75f : 2.875f); // {13,30,23}*0.125

    float px = fast_sigmoid(tx) + (float)gi;
    float py = fast_sigmoid(ty) + (float)gj;
    float pw = __builtin_amdgcn_exp2f(tw * LOG2E) * aw;
    float ph = __builtin_amdgcn_exp2f(th * LOG2E) * ah;

    // fix the box channels in dec (NT: dec lines are not cached; masked write)
    __builtin_nontemporal_store(px, &dec[base + 0]);
    __builtin_nontemporal_store(py, &dec[base + 1]);
    __builtin_nontemporal_store(pw, &dec[base + 2]);
    __builtin_nontemporal_store(ph, &dec[base + 3]);

    // replicate reference FP order: (val)/W * INPUTW
    float x1 = (px - pw * 0.5f) / 76.0f * 608.0f;
    float y1 = (py - ph * 0.5f) / 76.0f * 608.0f;
    float x2 = (px + pw * 0.5f) / 76.0f * 608.0f;
    float y2 = (py + ph * 0.5f) / 76.0f * 608.0f;
    float area2 = (x2 - x1) * (y2 - y1);
    float best = 0.0f;
#pragma unroll
    for (int m = 0; m < MM; ++m) {
        float4 gb = sbox[m];
        float area1 = (gb.z - gb.x) * (gb.w - gb.y);
        float ltx = fmaxf(gb.x, x1), lty = fmaxf(gb.y, y1);
        float rbx = fminf(gb.z, x2), rby = fminf(gb.w, y2);
        float inter = fmaxf(rbx - ltx, 0.0f) * fmaxf(rby - lty, 0.0f);
        float iou = inter * __builtin_amdgcn_rcpf(area1 + area2 - inter);
        best = fmaxf(best, iou);
    }
    noobj[idx] = (best <= 0.5f) ? 1.0f : 0.0f;
    obj[idx] = 0.0f;
}

// ---------------------------------------------------------------------------
// Kernel 3: per-GT best-anchor argmax. (unchanged; runs after kernel 2)
// ---------------------------------------------------------------------------
__global__ void assign_kernel(const float* __restrict__ gt,
                              float* __restrict__ noobj, float* __restrict__ obj) {
    int r = blockIdx.x * blockDim.x + threadIdx.x;
    if (r >= BB * MM) return;
    const float* g = gt + (size_t)r * 6;
    float cx = g[1], cy = g[2], gw = g[3], gh = g[4];
    float gx1 = (cx - gw * 0.5f) * 608.0f, gy1 = (cy - gh * 0.5f) * 608.0f;
    float gx2 = (cx + gw * 0.5f) * 608.0f, gy2 = (cy + gh * 0.5f) * 608.0f;
    float area_g = (gx2 - gx1) * (gy2 - gy1);
    int best = 0;
    float bestv = -1.0f;
#pragma unroll
    for (int k = 0; k < 9; ++k) {
        float ow = c_anchor[k][0] / 608.0f, oh = c_anchor[k][1] / 608.0f;
        float ax1 = (cx - ow * 0.5f) * 608.0f, ay1 = (cy - oh * 0.5f) * 608.0f;
        float ax2 = (cx + ow * 0.5f) * 608.0f, ay2 = (cy + oh * 0.5f) * 608.0f;
        float ltx = fmaxf(gx1, ax1), lty = fmaxf(gy1, ay1);
        float rbx = fminf(gx2, ax2), rby = fminf(gy2, ay2);
        float inter = fmaxf(rbx - ltx, 0.0f) * fmaxf(rby - lty, 0.0f);
        float area_a = (ax2 - ax1) * (ay2 - ay1);
        float v = inter / (area_g + area_a - inter);
        if (v > bestv) { bestv = v; best = k; }
    }
    if (best < AA) {
        int b = r / MM;
        int gi = (int)(cx * 76.0f);
        int gj = (int)(cy * 76.0f);
        int flat = ((b * AA + best) * WW + gi) * WW + gj;
        obj[flat] = 1.0f;
        noobj[flat] = 0.0f;
    }
}

extern "C" void kernel_launch(void* const* d_in, const int* in_sizes, int n_in,
                              void* d_out, int out_size, void* d_ws, size_t ws_size,
                              hipStream_t stream) {
    const float* pred = (const float*)d_in[0];
    const float* gt   = (const float*)d_in[1];
    float* dec   = (float*)d_out;            // 23,566,080
    float* noobj = dec + NDECODE;            //    277,248
    float* obj   = noobj + NCELLS;           //    277,248
    (void)d_ws; (void)ws_size;               // boxes scratch eliminated

    const int nblocks = (N4 + 1023) / 1024;  // 4 float4s/thread, wave-tiled
    decode_kernel<<<nblocks, 256, 0, stream>>>(
        (const vfloat4*)pred, (vfloat4*)dec);

    dim3 gb((CELLS_PER_IMG + 255) / 256, BB);
    noobj_kernel<<<gb, 256, 0, stream>>>(pred, gt, dec, noobj, obj);

    assign_kernel<<<2, 256, 0, stream>>>(gt, noobj, obj);
}